// Round 10
// baseline (246.486 us; speedup 1.0000x reference)
//
#include <hip/hip_runtime.h>
#include <cmath>

#define N_NODES    100000
#define N_EDGES    1600000
#define NUM_GRAPHS 64

// counting-sort geometry
#define BUCK_W     512                               // nodes per coarse bucket
#define NBUCK      196                               // ceil(100000/512)
#define EPB        2048                              // edges per partition block
#define NB1        782                               // ceil(1600000/2048)
#define GEMM_GS    782                               // grid-stride blocks for gemm1
#define FUSE_NPB   256                               // nodes per fused block
#define NFUSE      ((N_NODES + FUSE_NPB - 1) / FUSE_NPB)   // 391

typedef __attribute__((ext_vector_type(8))) short bf16x8;
typedef __attribute__((ext_vector_type(4))) float f32x4;

__device__ __forceinline__ ushort f2bf(float x) {
    union { float f; uint u; } v; v.f = x;
    uint r = v.u + 0x7fffu + ((v.u >> 16) & 1u);
    return (ushort)(r >> 16);
}
__device__ __forceinline__ float bf2f(ushort u) {
    union { uint u; float f; } v; v.u = ((uint)u) << 16;
    return v.f;
}

__device__ __forceinline__ void accum8(float* a, uint4 V) {
    uint w[4] = {V.x, V.y, V.z, V.w};
    #pragma unroll
    for (int j = 0; j < 4; ++j) {
        a[2 * j]     += bf2f((ushort)(w[j] & 0xffffu));
        a[2 * j + 1] += bf2f((ushort)(w[j] >> 16));
    }
}

// gather one node's aggregated channels [sub*8 .. sub*8+7] into a[8] (f32)
__device__ __forceinline__ void gather_node(
    const uint4* __restrict__ in4, const int* __restrict__ rowptr,
    const int* __restrict__ esrc, int node, int sub, float a[8])
{
    #pragma unroll
    for (int j = 0; j < 8; ++j) a[j] = 0.0f;
    accum8(a, in4[(size_t)node * 8 + sub]);   // self term
    int e = rowptr[node], end = rowptr[node + 1];
    for (; e + 8 <= end; e += 8) {
        int i0 = esrc[e],     i1 = esrc[e + 1], i2 = esrc[e + 2], i3 = esrc[e + 3];
        int i4 = esrc[e + 4], i5 = esrc[e + 5], i6 = esrc[e + 6], i7 = esrc[e + 7];
        uint4 v0 = in4[(size_t)i0 * 8 + sub];
        uint4 v1 = in4[(size_t)i1 * 8 + sub];
        uint4 v2 = in4[(size_t)i2 * 8 + sub];
        uint4 v3 = in4[(size_t)i3 * 8 + sub];
        uint4 v4 = in4[(size_t)i4 * 8 + sub];
        uint4 v5 = in4[(size_t)i5 * 8 + sub];
        uint4 v6 = in4[(size_t)i6 * 8 + sub];
        uint4 v7 = in4[(size_t)i7 * 8 + sub];
        accum8(a, v0); accum8(a, v1); accum8(a, v2); accum8(a, v3);
        accum8(a, v4); accum8(a, v5); accum8(a, v6); accum8(a, v7);
    }
    if (e + 4 <= end) {
        int i0 = esrc[e], i1 = esrc[e + 1], i2 = esrc[e + 2], i3 = esrc[e + 3];
        uint4 v0 = in4[(size_t)i0 * 8 + sub];
        uint4 v1 = in4[(size_t)i1 * 8 + sub];
        uint4 v2 = in4[(size_t)i2 * 8 + sub];
        uint4 v3 = in4[(size_t)i3 * 8 + sub];
        accum8(a, v0); accum8(a, v1); accum8(a, v2); accum8(a, v3);
        e += 4;
    }
    for (; e < end; ++e)
        accum8(a, in4[(size_t)esrc[e] * 8 + sub]);
}

// pack relu(a + bias) to 8 bf16 (one uint4)
__device__ __forceinline__ uint4 pack_relu(const float a[8], const float bg[8]) {
    uint4 o;
    o.x = (uint)f2bf(fmaxf(a[0] + bg[0], 0.0f)) | ((uint)f2bf(fmaxf(a[1] + bg[1], 0.0f)) << 16);
    o.y = (uint)f2bf(fmaxf(a[2] + bg[2], 0.0f)) | ((uint)f2bf(fmaxf(a[3] + bg[3], 0.0f)) << 16);
    o.z = (uint)f2bf(fmaxf(a[4] + bg[4], 0.0f)) | ((uint)f2bf(fmaxf(a[5] + bg[5], 0.0f)) << 16);
    o.w = (uint)f2bf(fmaxf(a[6] + bg[6], 0.0f)) | ((uint)f2bf(fmaxf(a[7] + bg[7], 0.0f)) << 16);
    return o;
}

// ========== K1: coarse histogram (blocks [0,NB1)) + gemm1 grid-stride (rest) ==========
__global__ __launch_bounds__(256) void k1_hist_gemm(
    const int* __restrict__ dst, int* __restrict__ bcount,
    const float* __restrict__ x, const float* __restrict__ W1,
    ushort* __restrict__ y)
{
    if (blockIdx.x < NB1) {
        __shared__ int shist[NBUCK];
        int tid = threadIdx.x;
        for (int i = tid; i < NBUCK; i += 256) shist[i] = 0;
        __syncthreads();
        int e0 = blockIdx.x * EPB + tid;
        #pragma unroll
        for (int k = 0; k < EPB / 256; ++k) {
            int e = e0 + k * 256;
            if (e < N_EDGES) atomicAdd(&shist[dst[e] >> 9], 1);
        }
        __syncthreads();
        for (int i = tid; i < NBUCK; i += 256)
            bcount[blockIdx.x * NBUCK + i] = shist[i];
        return;
    }
    int bid = blockIdx.x - NB1;
    int lane = threadIdx.x & 63, wave = threadIdx.x >> 6;
    int lg = lane >> 4, lm = lane & 15;

    bf16x8 Bf[4][4];
    #pragma unroll
    for (int kc = 0; kc < 4; ++kc)
        #pragma unroll
        for (int cb = 0; cb < 4; ++cb) {
            bf16x8 t;
            #pragma unroll
            for (int i = 0; i < 8; ++i)
                t[i] = (short)f2bf(W1[(kc * 32 + lg * 8 + i) * 64 + cb * 16 + lm]);
            Bf[kc][cb] = t;
        }

    const int ntiles = N_NODES / 16;   // 6250
    for (int tile = bid * 4 + wave; tile < ntiles; tile += GEMM_GS * 4) {
        int r = tile * 16 + lm;
        f32x4 acc[4] = {};
        #pragma unroll
        for (int kc = 0; kc < 4; ++kc) {
            const float* p = x + (size_t)r * 128 + kc * 32 + lg * 8;
            float4 a0 = *(const float4*)p;
            float4 a1 = *(const float4*)(p + 4);
            bf16x8 af;
            af[0] = (short)f2bf(a0.x); af[1] = (short)f2bf(a0.y);
            af[2] = (short)f2bf(a0.z); af[3] = (short)f2bf(a0.w);
            af[4] = (short)f2bf(a1.x); af[5] = (short)f2bf(a1.y);
            af[6] = (short)f2bf(a1.z); af[7] = (short)f2bf(a1.w);
            #pragma unroll
            for (int cb = 0; cb < 4; ++cb)
                acc[cb] = __builtin_amdgcn_mfma_f32_16x16x32_bf16(af, Bf[kc][cb], acc[cb], 0, 0, 0);
        }
        #pragma unroll
        for (int cb = 0; cb < 4; ++cb)
            #pragma unroll
            for (int i = 0; i < 4; ++i)
                y[(size_t)(tile * 16 + lg * 4 + i) * 64 + cb * 16 + lm] = f2bf(acc[cb][i]);
    }
}

// ========== P2a: per-bucket exclusive scan over NB1 block counts (parallel) ==========
#define SCH 4   // 256*4 = 1024 >= NB1
__global__ __launch_bounds__(256) void p2a_scan(
    const int* __restrict__ bcount, int* __restrict__ basetab,
    int* __restrict__ btot)
{
    __shared__ int sh[256];
    int b = blockIdx.x, tid = threadIdx.x;
    int v[SCH];
    int tsum = 0;
    #pragma unroll
    for (int j = 0; j < SCH; ++j) {
        int blk = tid * SCH + j;
        v[j] = (blk < NB1) ? bcount[(size_t)blk * NBUCK + b] : 0;
        tsum += v[j];
    }
    sh[tid] = tsum;
    __syncthreads();
    for (int off = 1; off < 256; off <<= 1) {
        int t = (tid >= off) ? sh[tid - off] : 0;
        __syncthreads();
        sh[tid] += t;
        __syncthreads();
    }
    if (tid == 255) btot[b] = sh[255];
    int excl = sh[tid] - tsum;
    #pragma unroll
    for (int j = 0; j < SCH; ++j) {
        int blk = tid * SCH + j;
        if (blk < NB1) basetab[(size_t)b * NB1 + blk] = excl;
        excl += v[j];
    }
}

// ========== P2b: exclusive scan of bucket totals -> gbase ; zero pooled ==========
__global__ __launch_bounds__(256) void p2b_scan(
    const int* __restrict__ btot, int* __restrict__ gbase,
    float* __restrict__ pooled)
{
    int tid = threadIdx.x;
    for (int i = tid; i < NUM_GRAPHS * 128; i += 256) pooled[i] = 0.0f;
    __shared__ int v[NBUCK];
    for (int j = tid; j < NBUCK; j += 256) v[j] = btot[j];
    __syncthreads();
    if (tid == 0) {
        int run = 0;
        for (int j = 0; j < NBUCK; ++j) { int t = v[j]; v[j] = run; run += t; }
        gbase[NBUCK] = run;   // == N_EDGES
    }
    __syncthreads();
    for (int j = tid; j < NBUCK; j += 256) gbase[j] = v[j];
}

// ========== P3: partition edges into bucket-major packed array ==========
__global__ __launch_bounds__(256) void p3_partition(
    const int* __restrict__ src, const int* __restrict__ dst,
    const int* __restrict__ basetab, const int* __restrict__ gbase,
    uint* __restrict__ epack)
{
    __shared__ int cur[NBUCK];
    int blk = blockIdx.x, tid = threadIdx.x;
    for (int i = tid; i < NBUCK; i += 256)
        cur[i] = basetab[(size_t)i * NB1 + blk] + gbase[i];
    __syncthreads();
    int e0 = blk * EPB + tid;
    #pragma unroll
    for (int k = 0; k < EPB / 256; ++k) {
        int e = e0 + k * 256;
        if (e < N_EDGES) {
            int d = dst[e], s = src[e];
            int bin = d >> 9;
            int pos = atomicAdd(&cur[bin], 1);
            epack[pos] = ((uint)(d & 511) << 17) | (uint)s;
        }
    }
}

// ========== P4: per-bucket fine CSR (rowptr + esrc), all LDS ==========
__global__ __launch_bounds__(256) void p4_fine(
    const uint* __restrict__ epack, const int* __restrict__ gbase,
    int* __restrict__ rowptr, int* __restrict__ esrc)
{
    __shared__ int hist[BUCK_W];
    int b = blockIdx.x, tid = threadIdx.x;
    int beg = gbase[b], end = gbase[b + 1];
    for (int i = tid; i < BUCK_W; i += 256) hist[i] = 0;
    __syncthreads();
    for (int e = beg + tid; e < end; e += 256)
        atomicAdd(&hist[epack[e] >> 17], 1);
    __syncthreads();
    if (tid == 0) {
        int run = 0;
        for (int i = 0; i < BUCK_W; ++i) { int t = hist[i]; hist[i] = run; run += t; }
    }
    __syncthreads();
    for (int i = tid; i < BUCK_W; i += 256) {
        int n = b * BUCK_W + i;
        if (n < N_NODES) rowptr[n] = beg + hist[i];
    }
    if (b == NBUCK - 1 && tid == 0) rowptr[N_NODES] = end;
    __syncthreads();
    for (int e = beg + tid; e < end; e += 256) {
        uint v = epack[e];
        int slot = beg + atomicAdd(&hist[v >> 17], 1);
        esrc[slot] = (int)(v & 0x1FFFFu);
    }
}

// ===== FUSED: agg1 (gather y -> LDS, +b1, relu) then MLP mid (GEMM2+GEMM3) =====
// Block = 256 nodes. LDS rows stored as 8 uint4 chunks, chunk XOR-swizzled by (row&7)
// so A-fragment ds_read (16 rows, same column) is 2-way instead of 16-way conflicted.
__global__ __launch_bounds__(256) void fused_agg_mid(
    const uint4* __restrict__ in4, const int* __restrict__ rowptr,
    const int* __restrict__ esrc, const float* __restrict__ b1,
    const float* __restrict__ W2, const float* __restrict__ b2,
    const float* __restrict__ W3, ushort* __restrict__ z)
{
    __shared__ uint4 srow4[FUSE_NPB * 8];             // 32 KB, bf16 rows (biased+relu'd)
    __shared__ __align__(16) float trs[4][16 * 68];   // per-wave transpose buffer
    __shared__ int pool;

    int tid = threadIdx.x;
    if (tid == 0) pool = 0;
    int lane = tid & 63, wave = tid >> 6;
    int lg = lane >> 4, lm = lane & 15;
    int sub = tid & 7;

    // weight fragments (independent of barrier)
    bf16x8 B2f[2][4], B3f[2][4];
    #pragma unroll
    for (int kc = 0; kc < 2; ++kc)
        #pragma unroll
        for (int cb = 0; cb < 4; ++cb) {
            bf16x8 t2, t3;
            #pragma unroll
            for (int i = 0; i < 8; ++i) {
                int k = kc * 32 + lg * 8 + i;
                int cc = cb * 16 + lm;
                t2[i] = (short)f2bf(W2[k * 64 + cc]);
                t3[i] = (short)f2bf(W3[k * 64 + cc]);
            }
            B2f[kc][cb] = t2; B3f[kc][cb] = t3;
        }
    float b2r[4];
    #pragma unroll
    for (int cb = 0; cb < 4; ++cb) b2r[cb] = b2[cb * 16 + lm];
    float bg[8];
    #pragma unroll
    for (int j = 0; j < 8; ++j) bg[j] = b1[sub * 8 + j];

    __syncthreads();   // pool visible

    int base = blockIdx.x * FUSE_NPB;
    int nmax = min(FUSE_NPB, N_NODES - base);

    // ---- phase 1: work-stealing gather into LDS ----
    for (;;) {
        int n = 0;
        if (sub == 0) n = atomicAdd(&pool, 1);
        n = __shfl(n, lane & 56, 64);
        if (n >= nmax) break;
        float a[8];
        gather_node(in4, rowptr, esrc, base + n, sub, a);
        srow4[n * 8 + (sub ^ (n & 7))] = pack_relu(a, bg);
    }
    __syncthreads();

    // ---- phase 2: each wave runs 4 tiles (64 rows) through GEMM2+GEMM3 ----
    #pragma unroll
    for (int t = 0; t < 4; ++t) {
        int lr0 = wave * 64 + t * 16;
        int gr0 = base + lr0;
        if (gr0 >= N_NODES) break;
        int lr = lr0 + lm;
        bf16x8 A1[2];
        #pragma unroll
        for (int kc = 0; kc < 2; ++kc)
            A1[kc] = *reinterpret_cast<const bf16x8*>(
                &srow4[lr * 8 + ((4 * kc + lg) ^ (lm & 7))]);
        f32x4 acc[4] = {};
        #pragma unroll
        for (int kc = 0; kc < 2; ++kc)
            #pragma unroll
            for (int cb = 0; cb < 4; ++cb)
                acc[cb] = __builtin_amdgcn_mfma_f32_16x16x32_bf16(A1[kc], B2f[kc][cb], acc[cb], 0, 0, 0);
        #pragma unroll
        for (int cb = 0; cb < 4; ++cb)
            #pragma unroll
            for (int i = 0; i < 4; ++i)
                trs[wave][(lg * 4 + i) * 68 + cb * 16 + lm] = fmaxf(acc[cb][i] + b2r[cb], 0.0f);
        bf16x8 A2[2];
        #pragma unroll
        for (int kc = 0; kc < 2; ++kc) {
            const float* p = &trs[wave][lm * 68 + kc * 32 + lg * 8];
            float4 u0 = *(const float4*)p;
            float4 u1 = *(const float4*)(p + 4);
            bf16x8 tt;
            tt[0] = (short)f2bf(u0.x); tt[1] = (short)f2bf(u0.y);
            tt[2] = (short)f2bf(u0.z); tt[3] = (short)f2bf(u0.w);
            tt[4] = (short)f2bf(u1.x); tt[5] = (short)f2bf(u1.y);
            tt[6] = (short)f2bf(u1.z); tt[7] = (short)f2bf(u1.w);
            A2[kc] = tt;
        }
        f32x4 acc2[4] = {};
        #pragma unroll
        for (int kc = 0; kc < 2; ++kc)
            #pragma unroll
            for (int cb = 0; cb < 4; ++cb)
                acc2[cb] = __builtin_amdgcn_mfma_f32_16x16x32_bf16(A2[kc], B3f[kc][cb], acc2[cb], 0, 0, 0);
        #pragma unroll
        for (int cb = 0; cb < 4; ++cb)
            #pragma unroll
            for (int i = 0; i < 4; ++i)
                z[(size_t)(gr0 + lg * 4 + i) * 64 + cb * 16 + lm] = f2bf(acc2[cb][i]);
    }
}

// ===== FUSED: agg2 (gather z -> LDS, +b3, relu) then GEMM4 + mean-pool =====
__global__ __launch_bounds__(256) void fused_agg_k4(
    const uint4* __restrict__ in4, const int* __restrict__ rowptr,
    const int* __restrict__ esrc, const float* __restrict__ b3,
    const float* __restrict__ W4, const float* __restrict__ b4,
    const int* __restrict__ batch, float* __restrict__ pooled)
{
    __shared__ uint4 srow4[FUSE_NPB * 8];   // 32 KB
    __shared__ int pool;

    int tid = threadIdx.x;
    if (tid == 0) pool = 0;
    int lane = tid & 63, wave = tid >> 6;
    int lg = lane >> 4, lm = lane & 15;
    int sub = tid & 7;

    bf16x8 B4f[2][8];
    #pragma unroll
    for (int kc = 0; kc < 2; ++kc)
        #pragma unroll
        for (int cb = 0; cb < 8; ++cb) {
            bf16x8 t;
            #pragma unroll
            for (int i = 0; i < 8; ++i)
                t[i] = (short)f2bf(W4[(kc * 32 + lg * 8 + i) * 128 + cb * 16 + lm]);
            B4f[kc][cb] = t;
        }
    float b4r[8];
    #pragma unroll
    for (int cb = 0; cb < 8; ++cb) b4r[cb] = b4[cb * 16 + lm];
    float bg[8];
    #pragma unroll
    for (int j = 0; j < 8; ++j) bg[j] = b3[sub * 8 + j];

    __syncthreads();

    int base = blockIdx.x * FUSE_NPB;
    int nmax = min(FUSE_NPB, N_NODES - base);

    // ---- phase 1: gather ----
    for (;;) {
        int n = 0;
        if (sub == 0) n = atomicAdd(&pool, 1);
        n = __shfl(n, lane & 56, 64);
        if (n >= nmax) break;
        float a[8];
        gather_node(in4, rowptr, esrc, base + n, sub, a);
        srow4[n * 8 + (sub ^ (n & 7))] = pack_relu(a, bg);
    }
    __syncthreads();

    // ---- phase 2: each wave does 4 tiles (64 consecutive rows) + pooling ----
    int gr_w = base + wave * 64;
    if (gr_w >= N_NODES) return;
    float pacc[8] = {0, 0, 0, 0, 0, 0, 0, 0};
    int curg = batch[gr_w];

#define FLUSH(G) do {                                                     \
        _Pragma("unroll")                                                 \
        for (int cb = 0; cb < 8; ++cb) {                                  \
            float v = pacc[cb];                                           \
            v += __shfl_xor(v, 16, 64);                                   \
            v += __shfl_xor(v, 32, 64);                                   \
            if (lane < 16) unsafeAtomicAdd(&pooled[(G) * 128 + cb * 16 + lm], v); \
            pacc[cb] = 0.0f;                                              \
        }                                                                 \
    } while (0)

    #pragma unroll
    for (int t = 0; t < 4; ++t) {
        int lr0 = wave * 64 + t * 16;
        int rbase = base + lr0;
        if (rbase >= N_NODES) break;
        int lr = lr0 + lm;
        bf16x8 A[2];
        #pragma unroll
        for (int kc = 0; kc < 2; ++kc)
            A[kc] = *reinterpret_cast<const bf16x8*>(
                &srow4[lr * 8 + ((4 * kc + lg) ^ (lm & 7))]);
        f32x4 acc[8] = {};
        #pragma unroll
        for (int kc = 0; kc < 2; ++kc)
            #pragma unroll
            for (int cb = 0; cb < 8; ++cb)
                acc[cb] = __builtin_amdgcn_mfma_f32_16x16x32_bf16(A[kc], B4f[kc][cb], acc[cb], 0, 0, 0);

        int g0 = batch[rbase], g15 = batch[rbase + 15];
        if (g0 != curg) { FLUSH(curg); curg = g0; }
        if (g0 == g15) {
            #pragma unroll
            for (int cb = 0; cb < 8; ++cb)
                pacc[cb] += acc[cb][0] + acc[cb][1] + acc[cb][2] + acc[cb][3]
                            + 4.0f * b4r[cb];
        } else {
            FLUSH(curg);
            #pragma unroll
            for (int i = 0; i < 4; ++i) {
                int gi = batch[rbase + lg * 4 + i];
                #pragma unroll
                for (int cb = 0; cb < 8; ++cb)
                    unsafeAtomicAdd(&pooled[gi * 128 + cb * 16 + lm],
                                    acc[cb][i] + b4r[cb]);
            }
            curg = g15;
        }
    }
    FLUSH(curg);
#undef FLUSH
}

// ================= head =================
__global__ void head_kernel(
    const float* __restrict__ pooled, const int* __restrict__ batch,
    const float* __restrict__ Wfc, const float* __restrict__ bfc,
    float* __restrict__ out)
{
    int g = threadIdx.x;
    if (g >= NUM_GRAPHS) return;

    int lo = 0, hi = N_NODES;
    while (lo < hi) { int mid = (lo + hi) >> 1; if (batch[mid] < g) lo = mid + 1; else hi = mid; }
    int beg = lo;
    lo = 0; hi = N_NODES;
    while (lo < hi) { int mid = (lo + hi) >> 1; if (batch[mid] < g + 1) lo = mid + 1; else hi = mid; }
    int cnt = lo - beg;
    float inv = 1.0f / fmaxf((float)cnt, 1.0f);

    float logits[10];
    for (int o = 0; o < 10; ++o) {
        float acc = 0.0f;
        for (int k = 0; k < 128; ++k)
            acc = fmaf(pooled[g * 128 + k], Wfc[k * 10 + o], acc);
        logits[o] = acc * inv + bfc[o];
    }
    float m = -INFINITY;
    for (int o = 0; o < 10; ++o) m = fmaxf(m, logits[o]);
    float s = 0.0f;
    for (int o = 0; o < 10; ++o) s += expf(logits[o] - m);
    float ls = logf(s);
    for (int o = 0; o < 10; ++o) out[g * 10 + o] = logits[o] - m - ls;
}

extern "C" void kernel_launch(void* const* d_in, const int* in_sizes, int n_in,
                              void* d_out, int out_size, void* d_ws, size_t ws_size,
                              hipStream_t stream)
{
    const float* x     = (const float*)d_in[0];
    const int*   ei    = (const int*)d_in[1];
    const int*   src   = ei;
    const int*   dst   = ei + N_EDGES;
    const int*   batch = (const int*)d_in[2];
    const float* W1  = (const float*)d_in[3];
    const float* b1  = (const float*)d_in[4];
    const float* W2  = (const float*)d_in[5];
    const float* b2  = (const float*)d_in[6];
    const float* W3  = (const float*)d_in[7];
    const float* b3  = (const float*)d_in[8];
    const float* W4  = (const float*)d_in[9];
    const float* b4  = (const float*)d_in[10];
    const float* Wfc = (const float*)d_in[11];
    const float* bfc = (const float*)d_in[12];
    float* out = (float*)d_out;

    char* ws = (char*)d_ws;
    ushort* bufA   = (ushort*)(ws);                 // 12.8 MB (y)
    ushort* bufB   = (ushort*)(ws + 12800000);      // 12.8 MB (z)
    int*  esrc     = (int*) (ws + 25600000);        // 6.4 MB
    uint* epack    = (uint*)(ws + 32000000);        // 6.4 MB
    int*  rowptr   = (int*) (ws + 38400000);        // 400,004 B
    int*  bcount   = (int*) (ws + 38800016);        // 613,088 B
    int*  basetab  = (int*) (ws + 39413120);        // 613,088 B
    int*  btot     = (int*) (ws + 40026224);        // 784 B
    int*  gbase    = (int*) (ws + 40027008);        // 788 B
    float* pooled  = (float*)(ws + 40027808);       // 32 KB

    // ---- K1: coarse hist + gemm1 ----
    k1_hist_gemm<<<NB1 + GEMM_GS, 256, 0, stream>>>(dst, bcount, x, W1, bufA);
    // ---- CSR build ----
    p2a_scan<<<NBUCK, 256, 0, stream>>>(bcount, basetab, btot);
    p2b_scan<<<1, 256, 0, stream>>>(btot, gbase, pooled);
    p3_partition<<<NB1, 256, 0, stream>>>(src, dst, basetab, gbase, epack);
    p4_fine<<<NBUCK, 256, 0, stream>>>(epack, gbase, rowptr, esrc);

    // ---- layer 1 fused: agg1 + MLP-mid ----
    fused_agg_mid<<<NFUSE, 256, 0, stream>>>(
        (const uint4*)bufA, rowptr, esrc, b1, W2, b2, W3, bufB);

    // ---- layer 2 fused: agg2 + GEMM4 + pool ----
    fused_agg_k4<<<NFUSE, 256, 0, stream>>>(
        (const uint4*)bufB, rowptr, esrc, b3, W4, b4, batch, pooled);

    head_kernel<<<1, 64, 0, stream>>>(pooled, batch, Wfc, bfc, out);
}

// Round 11
// 208.930 us; speedup vs baseline: 1.1798x; 1.1798x over previous
//
#include <hip/hip_runtime.h>
#include <cmath>

#define N_NODES    100000
#define N_EDGES    1600000
#define NUM_GRAPHS 64

// counting-sort geometry
#define BUCK_W     512                               // nodes per coarse bucket
#define NBUCK      196                               // ceil(100000/512)
#define EPB        2048                              // edges per partition block
#define NB1        782                               // ceil(1600000/2048)
#define GEMM_GS    782                               // grid-stride blocks for gemm1/fused_mid
#define AGG_NPB    64                                // nodes per agg block (1563 blocks)

typedef __attribute__((ext_vector_type(8))) short bf16x8;
typedef __attribute__((ext_vector_type(4))) float f32x4;

__device__ __forceinline__ ushort f2bf(float x) {
    union { float f; uint u; } v; v.f = x;
    uint r = v.u + 0x7fffu + ((v.u >> 16) & 1u);
    return (ushort)(r >> 16);
}
__device__ __forceinline__ float bf2f(ushort u) {
    union { uint u; float f; } v; v.u = ((uint)u) << 16;
    return v.f;
}

__device__ __forceinline__ void accum8(float* a, uint4 V) {
    uint w[4] = {V.x, V.y, V.z, V.w};
    #pragma unroll
    for (int j = 0; j < 4; ++j) {
        a[2 * j]     += bf2f((ushort)(w[j] & 0xffffu));
        a[2 * j + 1] += bf2f((ushort)(w[j] >> 16));
    }
}

// ========== K1: coarse histogram (blocks [0,NB1)) + gemm1 grid-stride (rest) ==========
__global__ __launch_bounds__(256) void k1_hist_gemm(
    const int* __restrict__ dst, int* __restrict__ bcount,
    const float* __restrict__ x, const float* __restrict__ W1,
    ushort* __restrict__ y)
{
    if (blockIdx.x < NB1) {
        __shared__ int shist[NBUCK];
        int tid = threadIdx.x;
        for (int i = tid; i < NBUCK; i += 256) shist[i] = 0;
        __syncthreads();
        int e0 = blockIdx.x * EPB + tid;
        #pragma unroll
        for (int k = 0; k < EPB / 256; ++k) {
            int e = e0 + k * 256;
            if (e < N_EDGES) atomicAdd(&shist[dst[e] >> 9], 1);
        }
        __syncthreads();
        for (int i = tid; i < NBUCK; i += 256)
            bcount[blockIdx.x * NBUCK + i] = shist[i];
        return;
    }
    int bid = blockIdx.x - NB1;
    int lane = threadIdx.x & 63, wave = threadIdx.x >> 6;
    int lg = lane >> 4, lm = lane & 15;

    bf16x8 Bf[4][4];
    #pragma unroll
    for (int kc = 0; kc < 4; ++kc)
        #pragma unroll
        for (int cb = 0; cb < 4; ++cb) {
            bf16x8 t;
            #pragma unroll
            for (int i = 0; i < 8; ++i)
                t[i] = (short)f2bf(W1[(kc * 32 + lg * 8 + i) * 64 + cb * 16 + lm]);
            Bf[kc][cb] = t;
        }

    const int ntiles = N_NODES / 16;   // 6250
    for (int tile = bid * 4 + wave; tile < ntiles; tile += GEMM_GS * 4) {
        int r = tile * 16 + lm;
        f32x4 acc[4] = {};
        #pragma unroll
        for (int kc = 0; kc < 4; ++kc) {
            const float* p = x + (size_t)r * 128 + kc * 32 + lg * 8;
            float4 a0 = *(const float4*)p;
            float4 a1 = *(const float4*)(p + 4);
            bf16x8 af;
            af[0] = (short)f2bf(a0.x); af[1] = (short)f2bf(a0.y);
            af[2] = (short)f2bf(a0.z); af[3] = (short)f2bf(a0.w);
            af[4] = (short)f2bf(a1.x); af[5] = (short)f2bf(a1.y);
            af[6] = (short)f2bf(a1.z); af[7] = (short)f2bf(a1.w);
            #pragma unroll
            for (int cb = 0; cb < 4; ++cb)
                acc[cb] = __builtin_amdgcn_mfma_f32_16x16x32_bf16(af, Bf[kc][cb], acc[cb], 0, 0, 0);
        }
        #pragma unroll
        for (int cb = 0; cb < 4; ++cb)
            #pragma unroll
            for (int i = 0; i < 4; ++i)
                y[(size_t)(tile * 16 + lg * 4 + i) * 64 + cb * 16 + lm] = f2bf(acc[cb][i]);
    }
}

// ========== P2a: per-bucket exclusive scan over NB1 block counts (parallel) ==========
#define SCH 4   // 256*4 = 1024 >= NB1
__global__ __launch_bounds__(256) void p2a_scan(
    const int* __restrict__ bcount, int* __restrict__ basetab,
    int* __restrict__ btot)
{
    __shared__ int sh[256];
    int b = blockIdx.x, tid = threadIdx.x;
    int v[SCH];
    int tsum = 0;
    #pragma unroll
    for (int j = 0; j < SCH; ++j) {
        int blk = tid * SCH + j;
        v[j] = (blk < NB1) ? bcount[(size_t)blk * NBUCK + b] : 0;
        tsum += v[j];
    }
    sh[tid] = tsum;
    __syncthreads();
    for (int off = 1; off < 256; off <<= 1) {
        int t = (tid >= off) ? sh[tid - off] : 0;
        __syncthreads();
        sh[tid] += t;
        __syncthreads();
    }
    if (tid == 255) btot[b] = sh[255];
    int excl = sh[tid] - tsum;
    #pragma unroll
    for (int j = 0; j < SCH; ++j) {
        int blk = tid * SCH + j;
        if (blk < NB1) basetab[(size_t)b * NB1 + blk] = excl;
        excl += v[j];
    }
}

// ========== P2b: exclusive scan of bucket totals -> gbase ; zero pooled ==========
__global__ __launch_bounds__(256) void p2b_scan(
    const int* __restrict__ btot, int* __restrict__ gbase,
    float* __restrict__ pooled)
{
    int tid = threadIdx.x;
    for (int i = tid; i < NUM_GRAPHS * 128; i += 256) pooled[i] = 0.0f;
    __shared__ int v[NBUCK];
    for (int j = tid; j < NBUCK; j += 256) v[j] = btot[j];
    __syncthreads();
    if (tid == 0) {
        int run = 0;
        for (int j = 0; j < NBUCK; ++j) { int t = v[j]; v[j] = run; run += t; }
        gbase[NBUCK] = run;   // == N_EDGES
    }
    __syncthreads();
    for (int j = tid; j < NBUCK; j += 256) gbase[j] = v[j];
}

// ========== P3: partition edges into bucket-major packed array ==========
__global__ __launch_bounds__(256) void p3_partition(
    const int* __restrict__ src, const int* __restrict__ dst,
    const int* __restrict__ basetab, const int* __restrict__ gbase,
    uint* __restrict__ epack)
{
    __shared__ int cur[NBUCK];
    int blk = blockIdx.x, tid = threadIdx.x;
    for (int i = tid; i < NBUCK; i += 256)
        cur[i] = basetab[(size_t)i * NB1 + blk] + gbase[i];
    __syncthreads();
    int e0 = blk * EPB + tid;
    #pragma unroll
    for (int k = 0; k < EPB / 256; ++k) {
        int e = e0 + k * 256;
        if (e < N_EDGES) {
            int d = dst[e], s = src[e];
            int bin = d >> 9;
            int pos = atomicAdd(&cur[bin], 1);
            epack[pos] = ((uint)(d & 511) << 17) | (uint)s;
        }
    }
}

// ========== P4: per-bucket fine CSR (rowptr + esrc), all LDS ==========
__global__ __launch_bounds__(256) void p4_fine(
    const uint* __restrict__ epack, const int* __restrict__ gbase,
    int* __restrict__ rowptr, int* __restrict__ esrc)
{
    __shared__ int hist[BUCK_W];
    int b = blockIdx.x, tid = threadIdx.x;
    int beg = gbase[b], end = gbase[b + 1];
    for (int i = tid; i < BUCK_W; i += 256) hist[i] = 0;
    __syncthreads();
    for (int e = beg + tid; e < end; e += 256)
        atomicAdd(&hist[epack[e] >> 17], 1);
    __syncthreads();
    if (tid == 0) {
        int run = 0;
        for (int i = 0; i < BUCK_W; ++i) { int t = hist[i]; hist[i] = run; run += t; }
    }
    __syncthreads();
    for (int i = tid; i < BUCK_W; i += 256) {
        int n = b * BUCK_W + i;
        if (n < N_NODES) rowptr[n] = beg + hist[i];
    }
    if (b == NBUCK - 1 && tid == 0) rowptr[N_NODES] = end;
    __syncthreads();
    for (int e = beg + tid; e < end; e += 256) {
        uint v = epack[e];
        int slot = beg + atomicAdd(&hist[v >> 17], 1);
        esrc[slot] = (int)(v & 0x1FFFFu);
    }
}

// ====== gather v5: 8-lane group pulls TWO nodes from LDS pool, interleaved 4+4 ======
// Doubles in-flight loads per lane vs v4 (16 uint4) without reducing block count.
__global__ __launch_bounds__(256) void agg_bf16_v5(
    const uint4* __restrict__ in4, uint4* __restrict__ out4,
    const int* __restrict__ rowptr, const int* __restrict__ esrc)
{
    __shared__ int pool;
    if (threadIdx.x == 0) pool = 0;
    __syncthreads();

    int sub = threadIdx.x & 7;
    int wl  = threadIdx.x & 63;        // lane within wave
    int base = blockIdx.x * AGG_NPB;
    int nmax = min(AGG_NPB, N_NODES - base);

    for (;;) {
        int n = 0;
        if (sub == 0) n = atomicAdd(&pool, 2);
        n = __shfl(n, wl & 56, 64);    // broadcast from group leader
        if (n >= nmax) break;
        int node0 = base + n;
        bool two = (n + 1 < nmax);
        int node1 = two ? node0 + 1 : node0;

        float a0[8] = {0,0,0,0,0,0,0,0};
        float a1[8] = {0,0,0,0,0,0,0,0};

        // self terms
        accum8(a0, in4[(size_t)node0 * 8 + sub]);
        if (two) accum8(a1, in4[(size_t)node1 * 8 + sub]);

        int e0 = rowptr[node0], f0 = rowptr[node0 + 1];
        int e1 = two ? rowptr[node1] : 0;
        int f1 = two ? rowptr[node1 + 1] : 0;

        // joint rounds: 4 edges of each node in flight (8 uint4 + next indices)
        while (e0 + 4 <= f0 && e1 + 4 <= f1) {
            int i00 = esrc[e0],     i01 = esrc[e0 + 1], i02 = esrc[e0 + 2], i03 = esrc[e0 + 3];
            int i10 = esrc[e1],     i11 = esrc[e1 + 1], i12 = esrc[e1 + 2], i13 = esrc[e1 + 3];
            uint4 v00 = in4[(size_t)i00 * 8 + sub];
            uint4 v01 = in4[(size_t)i01 * 8 + sub];
            uint4 v02 = in4[(size_t)i02 * 8 + sub];
            uint4 v03 = in4[(size_t)i03 * 8 + sub];
            uint4 v10 = in4[(size_t)i10 * 8 + sub];
            uint4 v11 = in4[(size_t)i11 * 8 + sub];
            uint4 v12 = in4[(size_t)i12 * 8 + sub];
            uint4 v13 = in4[(size_t)i13 * 8 + sub];
            accum8(a0, v00); accum8(a0, v01); accum8(a0, v02); accum8(a0, v03);
            accum8(a1, v10); accum8(a1, v11); accum8(a1, v12); accum8(a1, v13);
            e0 += 4; e1 += 4;
        }

#define DRAIN(E, F, A) do {                                                       \
        for (; (E) + 8 <= (F); (E) += 8) {                                        \
            int i0 = esrc[E],       i1 = esrc[(E) + 1], i2 = esrc[(E) + 2],       \
                i3 = esrc[(E) + 3], i4 = esrc[(E) + 4], i5 = esrc[(E) + 5],       \
                i6 = esrc[(E) + 6], i7 = esrc[(E) + 7];                           \
            uint4 v0 = in4[(size_t)i0 * 8 + sub];                                 \
            uint4 v1 = in4[(size_t)i1 * 8 + sub];                                 \
            uint4 v2 = in4[(size_t)i2 * 8 + sub];                                 \
            uint4 v3 = in4[(size_t)i3 * 8 + sub];                                 \
            uint4 v4 = in4[(size_t)i4 * 8 + sub];                                 \
            uint4 v5 = in4[(size_t)i5 * 8 + sub];                                 \
            uint4 v6 = in4[(size_t)i6 * 8 + sub];                                 \
            uint4 v7 = in4[(size_t)i7 * 8 + sub];                                 \
            accum8(A, v0); accum8(A, v1); accum8(A, v2); accum8(A, v3);           \
            accum8(A, v4); accum8(A, v5); accum8(A, v6); accum8(A, v7);           \
        }                                                                         \
        if ((E) + 4 <= (F)) {                                                     \
            int i0 = esrc[E], i1 = esrc[(E) + 1], i2 = esrc[(E) + 2],             \
                i3 = esrc[(E) + 3];                                               \
            uint4 v0 = in4[(size_t)i0 * 8 + sub];                                 \
            uint4 v1 = in4[(size_t)i1 * 8 + sub];                                 \
            uint4 v2 = in4[(size_t)i2 * 8 + sub];                                 \
            uint4 v3 = in4[(size_t)i3 * 8 + sub];                                 \
            accum8(A, v0); accum8(A, v1); accum8(A, v2); accum8(A, v3);           \
            (E) += 4;                                                             \
        }                                                                         \
        for (; (E) < (F); ++(E))                                                  \
            accum8(A, in4[(size_t)esrc[E] * 8 + sub]);                            \
    } while (0)

        DRAIN(e0, f0, a0);
        if (two) DRAIN(e1, f1, a1);
#undef DRAIN

        uint4 o0;
        o0.x = (uint)f2bf(a0[0]) | ((uint)f2bf(a0[1]) << 16);
        o0.y = (uint)f2bf(a0[2]) | ((uint)f2bf(a0[3]) << 16);
        o0.z = (uint)f2bf(a0[4]) | ((uint)f2bf(a0[5]) << 16);
        o0.w = (uint)f2bf(a0[6]) | ((uint)f2bf(a0[7]) << 16);
        out4[(size_t)node0 * 8 + sub] = o0;
        if (two) {
            uint4 o1;
            o1.x = (uint)f2bf(a1[0]) | ((uint)f2bf(a1[1]) << 16);
            o1.y = (uint)f2bf(a1[2]) | ((uint)f2bf(a1[3]) << 16);
            o1.z = (uint)f2bf(a1[4]) | ((uint)f2bf(a1[5]) << 16);
            o1.w = (uint)f2bf(a1[6]) | ((uint)f2bf(a1[7]) << 16);
            out4[(size_t)node1 * 8 + sub] = o1;
        }
    }
}

// ===== fused_mid: t=relu(yagg+b1); h1=relu(t@W2+b2); z=h1@W3 (bf16 MFMA, grid-stride) =====
__global__ __launch_bounds__(256) void fused_mid(
    const ushort* __restrict__ yagg, const float* __restrict__ b1,
    const float* __restrict__ W2, const float* __restrict__ b2,
    const float* __restrict__ W3, ushort* __restrict__ z)
{
    __shared__ __align__(16) float trs[4][16 * 68];
    int lane = threadIdx.x & 63, wave = threadIdx.x >> 6;
    int lg = lane >> 4, lm = lane & 15;

    bf16x8 B2[2][4], B3[2][4];
    #pragma unroll
    for (int kc = 0; kc < 2; ++kc)
        #pragma unroll
        for (int cb = 0; cb < 4; ++cb) {
            bf16x8 t2, t3;
            #pragma unroll
            for (int i = 0; i < 8; ++i) {
                int k = kc * 32 + lg * 8 + i;
                int cc = cb * 16 + lm;
                t2[i] = (short)f2bf(W2[k * 64 + cc]);
                t3[i] = (short)f2bf(W3[k * 64 + cc]);
            }
            B2[kc][cb] = t2; B3[kc][cb] = t3;
        }
    float b1r[2][8];
    #pragma unroll
    for (int kc = 0; kc < 2; ++kc)
        #pragma unroll
        for (int i = 0; i < 8; ++i)
            b1r[kc][i] = b1[kc * 32 + lg * 8 + i];
    float b2r[4];
    #pragma unroll
    for (int cb = 0; cb < 4; ++cb) b2r[cb] = b2[cb * 16 + lm];

    const int ntiles = N_NODES / 16;
    for (int tile = blockIdx.x * 4 + wave; tile < ntiles; tile += GEMM_GS * 4) {
        int r = tile * 16 + lm;
        bf16x8 A1[2];
        #pragma unroll
        for (int kc = 0; kc < 2; ++kc) {
            uint4 raw = *(const uint4*)(yagg + (size_t)r * 64 + kc * 32 + lg * 8);
            uint w[4] = {raw.x, raw.y, raw.z, raw.w};
            bf16x8 t;
            #pragma unroll
            for (int j = 0; j < 4; ++j) {
                float flo = bf2f((ushort)(w[j] & 0xffffu)) + b1r[kc][2 * j];
                float fhi = bf2f((ushort)(w[j] >> 16)) + b1r[kc][2 * j + 1];
                t[2 * j]     = (short)f2bf(fmaxf(flo, 0.0f));
                t[2 * j + 1] = (short)f2bf(fmaxf(fhi, 0.0f));
            }
            A1[kc] = t;
        }
        f32x4 acc[4] = {};
        #pragma unroll
        for (int kc = 0; kc < 2; ++kc)
            #pragma unroll
            for (int cb = 0; cb < 4; ++cb)
                acc[cb] = __builtin_amdgcn_mfma_f32_16x16x32_bf16(A1[kc], B2[kc][cb], acc[cb], 0, 0, 0);
        #pragma unroll
        for (int cb = 0; cb < 4; ++cb)
            #pragma unroll
            for (int i = 0; i < 4; ++i)
                trs[wave][(lg * 4 + i) * 68 + cb * 16 + lm] = fmaxf(acc[cb][i] + b2r[cb], 0.0f);
        bf16x8 A2[2];
        #pragma unroll
        for (int kc = 0; kc < 2; ++kc) {
            const float* p = &trs[wave][lm * 68 + kc * 32 + lg * 8];
            float4 u0 = *(const float4*)p;
            float4 u1 = *(const float4*)(p + 4);
            bf16x8 t;
            t[0] = (short)f2bf(u0.x); t[1] = (short)f2bf(u0.y);
            t[2] = (short)f2bf(u0.z); t[3] = (short)f2bf(u0.w);
            t[4] = (short)f2bf(u1.x); t[5] = (short)f2bf(u1.y);
            t[6] = (short)f2bf(u1.z); t[7] = (short)f2bf(u1.w);
            A2[kc] = t;
        }
        f32x4 acc2[4] = {};
        #pragma unroll
        for (int kc = 0; kc < 2; ++kc)
            #pragma unroll
            for (int cb = 0; cb < 4; ++cb)
                acc2[cb] = __builtin_amdgcn_mfma_f32_16x16x32_bf16(A2[kc], B3[kc][cb], acc2[cb], 0, 0, 0);
        #pragma unroll
        for (int cb = 0; cb < 4; ++cb)
            #pragma unroll
            for (int i = 0; i < 4; ++i)
                z[(size_t)(tile * 16 + lg * 4 + i) * 64 + cb * 16 + lm] = f2bf(acc2[cb][i]);
    }
}

// ===== k4 MFMA: o = relu(zagg+b3)@W4+b4 ; pooled[batch[r]] += o =====
__global__ __launch_bounds__(256) void k4_mfma_pool(
    const ushort* __restrict__ zagg, const float* __restrict__ b3,
    const float* __restrict__ W4, const float* __restrict__ b4,
    const int* __restrict__ batch, float* __restrict__ pooled)
{
    int lane = threadIdx.x & 63, wave = threadIdx.x >> 6;
    int lg = lane >> 4, lm = lane & 15;

    bf16x8 B4[2][8];
    #pragma unroll
    for (int kc = 0; kc < 2; ++kc)
        #pragma unroll
        for (int cb = 0; cb < 8; ++cb) {
            bf16x8 t;
            #pragma unroll
            for (int i = 0; i < 8; ++i)
                t[i] = (short)f2bf(W4[(kc * 32 + lg * 8 + i) * 128 + cb * 16 + lm]);
            B4[kc][cb] = t;
        }
    float b3r[2][8];
    #pragma unroll
    for (int kc = 0; kc < 2; ++kc)
        #pragma unroll
        for (int i = 0; i < 8; ++i)
            b3r[kc][i] = b3[kc * 32 + lg * 8 + i];
    float b4r[8];
    #pragma unroll
    for (int cb = 0; cb < 8; ++cb) b4r[cb] = b4[cb * 16 + lm];

    const int NT = N_NODES / 16;   // 6250
    const int TPW = 4;
    int w = blockIdx.x * 4 + wave;
    int t0 = w * TPW;
    if (t0 >= NT) return;
    int t1 = min(t0 + TPW, NT);

    float pacc[8] = {0, 0, 0, 0, 0, 0, 0, 0};
    int curg = batch[t0 * 16];

#define FLUSH(G) do {                                                     \
        _Pragma("unroll")                                                 \
        for (int cb = 0; cb < 8; ++cb) {                                  \
            float v = pacc[cb];                                           \
            v += __shfl_xor(v, 16, 64);                                   \
            v += __shfl_xor(v, 32, 64);                                   \
            if (lane < 16) unsafeAtomicAdd(&pooled[(G) * 128 + cb * 16 + lm], v); \
            pacc[cb] = 0.0f;                                              \
        }                                                                 \
    } while (0)

    for (int t = t0; t < t1; ++t) {
        int rbase = t * 16;
        int r = rbase + lm;
        bf16x8 A[2];
        #pragma unroll
        for (int kc = 0; kc < 2; ++kc) {
            uint4 raw = *(const uint4*)(zagg + (size_t)r * 64 + kc * 32 + lg * 8);
            uint wv[4] = {raw.x, raw.y, raw.z, raw.w};
            bf16x8 tt;
            #pragma unroll
            for (int j = 0; j < 4; ++j) {
                float flo = bf2f((ushort)(wv[j] & 0xffffu)) + b3r[kc][2 * j];
                float fhi = bf2f((ushort)(wv[j] >> 16))    + b3r[kc][2 * j + 1];
                tt[2 * j]     = (short)f2bf(fmaxf(flo, 0.0f));
                tt[2 * j + 1] = (short)f2bf(fmaxf(fhi, 0.0f));
            }
            A[kc] = tt;
        }
        f32x4 acc[8] = {};
        #pragma unroll
        for (int kc = 0; kc < 2; ++kc)
            #pragma unroll
            for (int cb = 0; cb < 8; ++cb)
                acc[cb] = __builtin_amdgcn_mfma_f32_16x16x32_bf16(A[kc], B4[kc][cb], acc[cb], 0, 0, 0);

        int g0 = batch[rbase], g15 = batch[rbase + 15];
        if (g0 != curg) { FLUSH(curg); curg = g0; }
        if (g0 == g15) {
            #pragma unroll
            for (int cb = 0; cb < 8; ++cb)
                pacc[cb] += acc[cb][0] + acc[cb][1] + acc[cb][2] + acc[cb][3]
                            + 4.0f * b4r[cb];
        } else {
            FLUSH(curg);
            #pragma unroll
            for (int i = 0; i < 4; ++i) {
                int gi = batch[rbase + lg * 4 + i];
                #pragma unroll
                for (int cb = 0; cb < 8; ++cb)
                    unsafeAtomicAdd(&pooled[gi * 128 + cb * 16 + lm],
                                    acc[cb][i] + b4r[cb]);
            }
            curg = g15;
        }
    }
    FLUSH(curg);
#undef FLUSH
}

// ================= head =================
__global__ void head_kernel(
    const float* __restrict__ pooled, const int* __restrict__ batch,
    const float* __restrict__ Wfc, const float* __restrict__ bfc,
    float* __restrict__ out)
{
    int g = threadIdx.x;
    if (g >= NUM_GRAPHS) return;

    int lo = 0, hi = N_NODES;
    while (lo < hi) { int mid = (lo + hi) >> 1; if (batch[mid] < g) lo = mid + 1; else hi = mid; }
    int beg = lo;
    lo = 0; hi = N_NODES;
    while (lo < hi) { int mid = (lo + hi) >> 1; if (batch[mid] < g + 1) lo = mid + 1; else hi = mid; }
    int cnt = lo - beg;
    float inv = 1.0f / fmaxf((float)cnt, 1.0f);

    float logits[10];
    for (int o = 0; o < 10; ++o) {
        float acc = 0.0f;
        for (int k = 0; k < 128; ++k)
            acc = fmaf(pooled[g * 128 + k], Wfc[k * 10 + o], acc);
        logits[o] = acc * inv + bfc[o];
    }
    float m = -INFINITY;
    for (int o = 0; o < 10; ++o) m = fmaxf(m, logits[o]);
    float s = 0.0f;
    for (int o = 0; o < 10; ++o) s += expf(logits[o] - m);
    float ls = logf(s);
    for (int o = 0; o < 10; ++o) out[g * 10 + o] = logits[o] - m - ls;
}

extern "C" void kernel_launch(void* const* d_in, const int* in_sizes, int n_in,
                              void* d_out, int out_size, void* d_ws, size_t ws_size,
                              hipStream_t stream)
{
    const float* x     = (const float*)d_in[0];
    const int*   ei    = (const int*)d_in[1];
    const int*   src   = ei;
    const int*   dst   = ei + N_EDGES;
    const int*   batch = (const int*)d_in[2];
    const float* W1  = (const float*)d_in[3];
    const float* b1  = (const float*)d_in[4];
    const float* W2  = (const float*)d_in[5];
    const float* b2  = (const float*)d_in[6];
    const float* W3  = (const float*)d_in[7];
    const float* b3  = (const float*)d_in[8];
    const float* W4  = (const float*)d_in[9];
    const float* b4  = (const float*)d_in[10];
    const float* Wfc = (const float*)d_in[11];
    const float* bfc = (const float*)d_in[12];
    float* out = (float*)d_out;

    char* ws = (char*)d_ws;
    ushort* bufA   = (ushort*)(ws);                 // 12.8 MB
    ushort* bufB   = (ushort*)(ws + 12800000);      // 12.8 MB
    int*  esrc     = (int*) (ws + 25600000);        // 6.4 MB
    uint* epack    = (uint*)(ws + 32000000);        // 6.4 MB
    int*  rowptr   = (int*) (ws + 38400000);        // 400,004 B
    int*  bcount   = (int*) (ws + 38800016);        // 782*196*4 = 613,088 B
    int*  basetab  = (int*) (ws + 39413120);        // 613,088 B
    int*  btot     = (int*) (ws + 40026224);        // 784 B
    int*  gbase    = (int*) (ws + 40027008);        // 788 B
    float* pooled  = (float*)(ws + 40027808);       // 32 KB

    // ---- K1: coarse hist + gemm1 (grid-stride) ----
    k1_hist_gemm<<<NB1 + GEMM_GS, 256, 0, stream>>>(dst, bcount, x, W1, bufA);
    // ---- CSR build ----
    p2a_scan<<<NBUCK, 256, 0, stream>>>(bcount, basetab, btot);
    p2b_scan<<<1, 256, 0, stream>>>(btot, gbase, pooled);
    p3_partition<<<NB1, 256, 0, stream>>>(src, dst, basetab, gbase, epack);
    p4_fine<<<NBUCK, 256, 0, stream>>>(epack, gbase, rowptr, esrc);

    // ---- layer 1 ----
    agg_bf16_v5<<<(N_NODES + AGG_NPB - 1) / AGG_NPB, 256, 0, stream>>>(
        (const uint4*)bufA, (uint4*)bufB, rowptr, esrc);
    fused_mid<<<GEMM_GS, 256, 0, stream>>>(bufB, b1, W2, b2, W3, bufA);

    // ---- layer 2 ----
    agg_bf16_v5<<<(N_NODES + AGG_NPB - 1) / AGG_NPB, 256, 0, stream>>>(
        (const uint4*)bufA, (uint4*)bufB, rowptr, esrc);
    {
        const int NT = N_NODES / 16;   // 6250
        const int TPW = 4;
        int blocks = (NT + 4 * TPW - 1) / (4 * TPW);   // 391
        k4_mfma_pool<<<blocks, 256, 0, stream>>>(bufB, b3, W4, b4, batch, pooled);
    }

    head_kernel<<<1, 64, 0, stream>>>(pooled, batch, Wfc, bfc, out);
}

// Round 12
// 173.705 us; speedup vs baseline: 1.4190x; 1.2028x over previous
//
#include <hip/hip_runtime.h>
#include <cmath>

#define N_NODES    100000
#define N_EDGES    1600000
#define NUM_GRAPHS 64

// counting-sort geometry
#define BUCK_W     512                               // nodes per coarse bucket
#define NBUCK      196                               // ceil(100000/512)
#define EPB        2048                              // edges per partition block
#define NB1        782                               // ceil(1600000/2048)
#define GEMM_GS    782                               // grid-stride blocks for gemm1/fused_mid
#define AGG_NPB    64                                // nodes per agg block (1563 blocks)

typedef __attribute__((ext_vector_type(8))) short bf16x8;
typedef __attribute__((ext_vector_type(4))) float f32x4;
typedef __attribute__((ext_vector_type(2))) float f32x2;

__device__ __forceinline__ ushort f2bf(float x) {
    union { float f; uint u; } v; v.f = x;
    uint r = v.u + 0x7fffu + ((v.u >> 16) & 1u);
    return (ushort)(r >> 16);
}
__device__ __forceinline__ float bf2f(ushort u) {
    union { uint u; float f; } v; v.u = ((uint)u) << 16;
    return v.f;
}
// f32 -> fp8 e4m3 (OCP) via HW converter, low byte
__device__ __forceinline__ unsigned char f2fp8(float v) {
    int p = __builtin_amdgcn_cvt_pk_fp8_f32(v, v, 0, false);
    return (unsigned char)(p & 0xFF);
}
// accumulate 8 fp8 channels (one uint2) into f32 accumulators
__device__ __forceinline__ void accum8_fp8(float* a, uint2 V) {
    f32x2 d0 = __builtin_amdgcn_cvt_pk_f32_fp8((int)V.x, false);
    f32x2 d1 = __builtin_amdgcn_cvt_pk_f32_fp8((int)V.x, true);
    f32x2 d2 = __builtin_amdgcn_cvt_pk_f32_fp8((int)V.y, false);
    f32x2 d3 = __builtin_amdgcn_cvt_pk_f32_fp8((int)V.y, true);
    a[0] += d0.x; a[1] += d0.y; a[2] += d1.x; a[3] += d1.y;
    a[4] += d2.x; a[5] += d2.y; a[6] += d3.x; a[7] += d3.y;
}

// ========== K1: coarse histogram (blocks [0,NB1)) + gemm1 grid-stride (rest) ==========
// gemm1 emits y in fp8 e4m3 (the gathered representation).
__global__ __launch_bounds__(256) void k1_hist_gemm(
    const int* __restrict__ dst, int* __restrict__ bcount,
    const float* __restrict__ x, const float* __restrict__ W1,
    unsigned char* __restrict__ y8)
{
    if (blockIdx.x < NB1) {
        __shared__ int shist[NBUCK];
        int tid = threadIdx.x;
        for (int i = tid; i < NBUCK; i += 256) shist[i] = 0;
        __syncthreads();
        int e0 = blockIdx.x * EPB + tid;
        #pragma unroll
        for (int k = 0; k < EPB / 256; ++k) {
            int e = e0 + k * 256;
            if (e < N_EDGES) atomicAdd(&shist[dst[e] >> 9], 1);
        }
        __syncthreads();
        for (int i = tid; i < NBUCK; i += 256)
            bcount[blockIdx.x * NBUCK + i] = shist[i];
        return;
    }
    int bid = blockIdx.x - NB1;
    int lane = threadIdx.x & 63, wave = threadIdx.x >> 6;
    int lg = lane >> 4, lm = lane & 15;

    bf16x8 Bf[4][4];
    #pragma unroll
    for (int kc = 0; kc < 4; ++kc)
        #pragma unroll
        for (int cb = 0; cb < 4; ++cb) {
            bf16x8 t;
            #pragma unroll
            for (int i = 0; i < 8; ++i)
                t[i] = (short)f2bf(W1[(kc * 32 + lg * 8 + i) * 64 + cb * 16 + lm]);
            Bf[kc][cb] = t;
        }

    const int ntiles = N_NODES / 16;   // 6250
    for (int tile = bid * 4 + wave; tile < ntiles; tile += GEMM_GS * 4) {
        int r = tile * 16 + lm;
        f32x4 acc[4] = {};
        #pragma unroll
        for (int kc = 0; kc < 4; ++kc) {
            const float* p = x + (size_t)r * 128 + kc * 32 + lg * 8;
            float4 a0 = *(const float4*)p;
            float4 a1 = *(const float4*)(p + 4);
            bf16x8 af;
            af[0] = (short)f2bf(a0.x); af[1] = (short)f2bf(a0.y);
            af[2] = (short)f2bf(a0.z); af[3] = (short)f2bf(a0.w);
            af[4] = (short)f2bf(a1.x); af[5] = (short)f2bf(a1.y);
            af[6] = (short)f2bf(a1.z); af[7] = (short)f2bf(a1.w);
            #pragma unroll
            for (int cb = 0; cb < 4; ++cb)
                acc[cb] = __builtin_amdgcn_mfma_f32_16x16x32_bf16(af, Bf[kc][cb], acc[cb], 0, 0, 0);
        }
        #pragma unroll
        for (int cb = 0; cb < 4; ++cb)
            #pragma unroll
            for (int i = 0; i < 4; ++i)
                y8[(size_t)(tile * 16 + lg * 4 + i) * 64 + cb * 16 + lm] = f2fp8(acc[cb][i]);
    }
}

// ========== P2a: per-bucket exclusive scan over NB1 block counts (parallel) ==========
#define SCH 4   // 256*4 = 1024 >= NB1
__global__ __launch_bounds__(256) void p2a_scan(
    const int* __restrict__ bcount, int* __restrict__ basetab,
    int* __restrict__ btot)
{
    __shared__ int sh[256];
    int b = blockIdx.x, tid = threadIdx.x;
    int v[SCH];
    int tsum = 0;
    #pragma unroll
    for (int j = 0; j < SCH; ++j) {
        int blk = tid * SCH + j;
        v[j] = (blk < NB1) ? bcount[(size_t)blk * NBUCK + b] : 0;
        tsum += v[j];
    }
    sh[tid] = tsum;
    __syncthreads();
    for (int off = 1; off < 256; off <<= 1) {
        int t = (tid >= off) ? sh[tid - off] : 0;
        __syncthreads();
        sh[tid] += t;
        __syncthreads();
    }
    if (tid == 255) btot[b] = sh[255];
    int excl = sh[tid] - tsum;
    #pragma unroll
    for (int j = 0; j < SCH; ++j) {
        int blk = tid * SCH + j;
        if (blk < NB1) basetab[(size_t)b * NB1 + blk] = excl;
        excl += v[j];
    }
}

// ========== P2b: exclusive scan of bucket totals -> gbase ; zero pooled ==========
__global__ __launch_bounds__(256) void p2b_scan(
    const int* __restrict__ btot, int* __restrict__ gbase,
    float* __restrict__ pooled)
{
    int tid = threadIdx.x;
    for (int i = tid; i < NUM_GRAPHS * 128; i += 256) pooled[i] = 0.0f;
    __shared__ int v[NBUCK];
    for (int j = tid; j < NBUCK; j += 256) v[j] = btot[j];
    __syncthreads();
    if (tid == 0) {
        int run = 0;
        for (int j = 0; j < NBUCK; ++j) { int t = v[j]; v[j] = run; run += t; }
        gbase[NBUCK] = run;   // == N_EDGES
    }
    __syncthreads();
    for (int j = tid; j < NBUCK; j += 256) gbase[j] = v[j];
}

// ========== P3: partition edges into bucket-major packed array ==========
__global__ __launch_bounds__(256) void p3_partition(
    const int* __restrict__ src, const int* __restrict__ dst,
    const int* __restrict__ basetab, const int* __restrict__ gbase,
    uint* __restrict__ epack)
{
    __shared__ int cur[NBUCK];
    int blk = blockIdx.x, tid = threadIdx.x;
    for (int i = tid; i < NBUCK; i += 256)
        cur[i] = basetab[(size_t)i * NB1 + blk] + gbase[i];
    __syncthreads();
    int e0 = blk * EPB + tid;
    #pragma unroll
    for (int k = 0; k < EPB / 256; ++k) {
        int e = e0 + k * 256;
        if (e < N_EDGES) {
            int d = dst[e], s = src[e];
            int bin = d >> 9;
            int pos = atomicAdd(&cur[bin], 1);
            epack[pos] = ((uint)(d & 511) << 17) | (uint)s;
        }
    }
}

// ========== P4: per-bucket fine CSR (rowptr + esrc), all LDS ==========
__global__ __launch_bounds__(256) void p4_fine(
    const uint* __restrict__ epack, const int* __restrict__ gbase,
    int* __restrict__ rowptr, int* __restrict__ esrc)
{
    __shared__ int hist[BUCK_W];
    int b = blockIdx.x, tid = threadIdx.x;
    int beg = gbase[b], end = gbase[b + 1];
    for (int i = tid; i < BUCK_W; i += 256) hist[i] = 0;
    __syncthreads();
    for (int e = beg + tid; e < end; e += 256)
        atomicAdd(&hist[epack[e] >> 17], 1);
    __syncthreads();
    if (tid == 0) {
        int run = 0;
        for (int i = 0; i < BUCK_W; ++i) { int t = hist[i]; hist[i] = run; run += t; }
    }
    __syncthreads();
    for (int i = tid; i < BUCK_W; i += 256) {
        int n = b * BUCK_W + i;
        if (n < N_NODES) rowptr[n] = beg + hist[i];
    }
    if (b == NBUCK - 1 && tid == 0) rowptr[N_NODES] = end;
    __syncthreads();
    for (int e = beg + tid; e < end; e += 256) {
        uint v = epack[e];
        int slot = beg + atomicAdd(&hist[v >> 17], 1);
        esrc[slot] = (int)(v & 0x1FFFFu);
    }
}

// ====== gather fp8 (v4 structure): 8-lane group per node, work-steal pool ======
// Input rows are 64 ch fp8 = 64 B; each lane loads uint2 (8 ch), f32-accumulates,
// output written as bf16 (128 B rows) for the MFMA consumers.
__global__ __launch_bounds__(256) void agg_fp8(
    const uint2* __restrict__ in8, uint4* __restrict__ out4,
    const int* __restrict__ rowptr, const int* __restrict__ esrc)
{
    __shared__ int pool;
    if (threadIdx.x == 0) pool = 0;
    __syncthreads();

    int sub = threadIdx.x & 7;
    int wl  = threadIdx.x & 63;
    int base = blockIdx.x * AGG_NPB;
    int nmax = min(AGG_NPB, N_NODES - base);

    for (;;) {
        int n = 0;
        if (sub == 0) n = atomicAdd(&pool, 1);
        n = __shfl(n, wl & 56, 64);    // broadcast from group leader
        if (n >= nmax) break;
        int node = base + n;

        float a[8] = {0, 0, 0, 0, 0, 0, 0, 0};
        accum8_fp8(a, in8[(size_t)node * 8 + sub]);   // self term

        int e = rowptr[node], end = rowptr[node + 1];
        for (; e + 8 <= end; e += 8) {
            int i0 = esrc[e],     i1 = esrc[e + 1], i2 = esrc[e + 2], i3 = esrc[e + 3];
            int i4 = esrc[e + 4], i5 = esrc[e + 5], i6 = esrc[e + 6], i7 = esrc[e + 7];
            uint2 v0 = in8[(size_t)i0 * 8 + sub];
            uint2 v1 = in8[(size_t)i1 * 8 + sub];
            uint2 v2 = in8[(size_t)i2 * 8 + sub];
            uint2 v3 = in8[(size_t)i3 * 8 + sub];
            uint2 v4 = in8[(size_t)i4 * 8 + sub];
            uint2 v5 = in8[(size_t)i5 * 8 + sub];
            uint2 v6 = in8[(size_t)i6 * 8 + sub];
            uint2 v7 = in8[(size_t)i7 * 8 + sub];
            accum8_fp8(a, v0); accum8_fp8(a, v1); accum8_fp8(a, v2); accum8_fp8(a, v3);
            accum8_fp8(a, v4); accum8_fp8(a, v5); accum8_fp8(a, v6); accum8_fp8(a, v7);
        }
        if (e + 4 <= end) {
            int i0 = esrc[e], i1 = esrc[e + 1], i2 = esrc[e + 2], i3 = esrc[e + 3];
            uint2 v0 = in8[(size_t)i0 * 8 + sub];
            uint2 v1 = in8[(size_t)i1 * 8 + sub];
            uint2 v2 = in8[(size_t)i2 * 8 + sub];
            uint2 v3 = in8[(size_t)i3 * 8 + sub];
            accum8_fp8(a, v0); accum8_fp8(a, v1); accum8_fp8(a, v2); accum8_fp8(a, v3);
            e += 4;
        }
        for (; e < end; ++e)
            accum8_fp8(a, in8[(size_t)esrc[e] * 8 + sub]);

        uint4 o;
        o.x = (uint)f2bf(a[0]) | ((uint)f2bf(a[1]) << 16);
        o.y = (uint)f2bf(a[2]) | ((uint)f2bf(a[3]) << 16);
        o.z = (uint)f2bf(a[4]) | ((uint)f2bf(a[5]) << 16);
        o.w = (uint)f2bf(a[6]) | ((uint)f2bf(a[7]) << 16);
        out4[(size_t)node * 8 + sub] = o;
    }
}

// ===== fused_mid: t=relu(yagg+b1); h1=relu(t@W2+b2); z=h1@W3 (bf16 MFMA, fp8 out) =====
__global__ __launch_bounds__(256) void fused_mid(
    const ushort* __restrict__ yagg, const float* __restrict__ b1,
    const float* __restrict__ W2, const float* __restrict__ b2,
    const float* __restrict__ W3, unsigned char* __restrict__ z8)
{
    __shared__ __align__(16) float trs[4][16 * 68];
    int lane = threadIdx.x & 63, wave = threadIdx.x >> 6;
    int lg = lane >> 4, lm = lane & 15;

    bf16x8 B2[2][4], B3[2][4];
    #pragma unroll
    for (int kc = 0; kc < 2; ++kc)
        #pragma unroll
        for (int cb = 0; cb < 4; ++cb) {
            bf16x8 t2, t3;
            #pragma unroll
            for (int i = 0; i < 8; ++i) {
                int k = kc * 32 + lg * 8 + i;
                int cc = cb * 16 + lm;
                t2[i] = (short)f2bf(W2[k * 64 + cc]);
                t3[i] = (short)f2bf(W3[k * 64 + cc]);
            }
            B2[kc][cb] = t2; B3[kc][cb] = t3;
        }
    float b1r[2][8];
    #pragma unroll
    for (int kc = 0; kc < 2; ++kc)
        #pragma unroll
        for (int i = 0; i < 8; ++i)
            b1r[kc][i] = b1[kc * 32 + lg * 8 + i];
    float b2r[4];
    #pragma unroll
    for (int cb = 0; cb < 4; ++cb) b2r[cb] = b2[cb * 16 + lm];

    const int ntiles = N_NODES / 16;
    for (int tile = blockIdx.x * 4 + wave; tile < ntiles; tile += GEMM_GS * 4) {
        int r = tile * 16 + lm;
        bf16x8 A1[2];
        #pragma unroll
        for (int kc = 0; kc < 2; ++kc) {
            uint4 raw = *(const uint4*)(yagg + (size_t)r * 64 + kc * 32 + lg * 8);
            uint w[4] = {raw.x, raw.y, raw.z, raw.w};
            bf16x8 t;
            #pragma unroll
            for (int j = 0; j < 4; ++j) {
                float flo = bf2f((ushort)(w[j] & 0xffffu)) + b1r[kc][2 * j];
                float fhi = bf2f((ushort)(w[j] >> 16)) + b1r[kc][2 * j + 1];
                t[2 * j]     = (short)f2bf(fmaxf(flo, 0.0f));
                t[2 * j + 1] = (short)f2bf(fmaxf(fhi, 0.0f));
            }
            A1[kc] = t;
        }
        f32x4 acc[4] = {};
        #pragma unroll
        for (int kc = 0; kc < 2; ++kc)
            #pragma unroll
            for (int cb = 0; cb < 4; ++cb)
                acc[cb] = __builtin_amdgcn_mfma_f32_16x16x32_bf16(A1[kc], B2[kc][cb], acc[cb], 0, 0, 0);
        #pragma unroll
        for (int cb = 0; cb < 4; ++cb)
            #pragma unroll
            for (int i = 0; i < 4; ++i)
                trs[wave][(lg * 4 + i) * 68 + cb * 16 + lm] = fmaxf(acc[cb][i] + b2r[cb], 0.0f);
        bf16x8 A2[2];
        #pragma unroll
        for (int kc = 0; kc < 2; ++kc) {
            const float* p = &trs[wave][lm * 68 + kc * 32 + lg * 8];
            float4 u0 = *(const float4*)p;
            float4 u1 = *(const float4*)(p + 4);
            bf16x8 t;
            t[0] = (short)f2bf(u0.x); t[1] = (short)f2bf(u0.y);
            t[2] = (short)f2bf(u0.z); t[3] = (short)f2bf(u0.w);
            t[4] = (short)f2bf(u1.x); t[5] = (short)f2bf(u1.y);
            t[6] = (short)f2bf(u1.z); t[7] = (short)f2bf(u1.w);
            A2[kc] = t;
        }
        f32x4 acc2[4] = {};
        #pragma unroll
        for (int kc = 0; kc < 2; ++kc)
            #pragma unroll
            for (int cb = 0; cb < 4; ++cb)
                acc2[cb] = __builtin_amdgcn_mfma_f32_16x16x32_bf16(A2[kc], B3[kc][cb], acc2[cb], 0, 0, 0);
        #pragma unroll
        for (int cb = 0; cb < 4; ++cb)
            #pragma unroll
            for (int i = 0; i < 4; ++i)
                z8[(size_t)(tile * 16 + lg * 4 + i) * 64 + cb * 16 + lm] = f2fp8(acc2[cb][i]);
    }
}

// ===== k4 MFMA: o = relu(zagg+b3)@W4+b4 ; pooled[batch[r]] += o =====
__global__ __launch_bounds__(256) void k4_mfma_pool(
    const ushort* __restrict__ zagg, const float* __restrict__ b3,
    const float* __restrict__ W4, const float* __restrict__ b4,
    const int* __restrict__ batch, float* __restrict__ pooled)
{
    int lane = threadIdx.x & 63, wave = threadIdx.x >> 6;
    int lg = lane >> 4, lm = lane & 15;

    bf16x8 B4[2][8];
    #pragma unroll
    for (int kc = 0; kc < 2; ++kc)
        #pragma unroll
        for (int cb = 0; cb < 8; ++cb) {
            bf16x8 t;
            #pragma unroll
            for (int i = 0; i < 8; ++i)
                t[i] = (short)f2bf(W4[(kc * 32 + lg * 8 + i) * 128 + cb * 16 + lm]);
            B4[kc][cb] = t;
        }
    float b3r[2][8];
    #pragma unroll
    for (int kc = 0; kc < 2; ++kc)
        #pragma unroll
        for (int i = 0; i < 8; ++i)
            b3r[kc][i] = b3[kc * 32 + lg * 8 + i];
    float b4r[8];
    #pragma unroll
    for (int cb = 0; cb < 8; ++cb) b4r[cb] = b4[cb * 16 + lm];

    const int NT = N_NODES / 16;   // 6250
    const int TPW = 4;
    int w = blockIdx.x * 4 + wave;
    int t0 = w * TPW;
    if (t0 >= NT) return;
    int t1 = min(t0 + TPW, NT);

    float pacc[8] = {0, 0, 0, 0, 0, 0, 0, 0};
    int curg = batch[t0 * 16];

#define FLUSH(G) do {                                                     \
        _Pragma("unroll")                                                 \
        for (int cb = 0; cb < 8; ++cb) {                                  \
            float v = pacc[cb];                                           \
            v += __shfl_xor(v, 16, 64);                                   \
            v += __shfl_xor(v, 32, 64);                                   \
            if (lane < 16) unsafeAtomicAdd(&pooled[(G) * 128 + cb * 16 + lm], v); \
            pacc[cb] = 0.0f;                                              \
        }                                                                 \
    } while (0)

    for (int t = t0; t < t1; ++t) {
        int rbase = t * 16;
        int r = rbase + lm;
        bf16x8 A[2];
        #pragma unroll
        for (int kc = 0; kc < 2; ++kc) {
            uint4 raw = *(const uint4*)(zagg + (size_t)r * 64 + kc * 32 + lg * 8);
            uint wv[4] = {raw.x, raw.y, raw.z, raw.w};
            bf16x8 tt;
            #pragma unroll
            for (int j = 0; j < 4; ++j) {
                float flo = bf2f((ushort)(wv[j] & 0xffffu)) + b3r[kc][2 * j];
                float fhi = bf2f((ushort)(wv[j] >> 16))    + b3r[kc][2 * j + 1];
                tt[2 * j]     = (short)f2bf(fmaxf(flo, 0.0f));
                tt[2 * j + 1] = (short)f2bf(fmaxf(fhi, 0.0f));
            }
            A[kc] = tt;
        }
        f32x4 acc[8] = {};
        #pragma unroll
        for (int kc = 0; kc < 2; ++kc)
            #pragma unroll
            for (int cb = 0; cb < 8; ++cb)
                acc[cb] = __builtin_amdgcn_mfma_f32_16x16x32_bf16(A[kc], B4[kc][cb], acc[cb], 0, 0, 0);

        int g0 = batch[rbase], g15 = batch[rbase + 15];
        if (g0 != curg) { FLUSH(curg); curg = g0; }
        if (g0 == g15) {
            #pragma unroll
            for (int cb = 0; cb < 8; ++cb)
                pacc[cb] += acc[cb][0] + acc[cb][1] + acc[cb][2] + acc[cb][3]
                            + 4.0f * b4r[cb];
        } else {
            FLUSH(curg);
            #pragma unroll
            for (int i = 0; i < 4; ++i) {
                int gi = batch[rbase + lg * 4 + i];
                #pragma unroll
                for (int cb = 0; cb < 8; ++cb)
                    unsafeAtomicAdd(&pooled[gi * 128 + cb * 16 + lm],
                                    acc[cb][i] + b4r[cb]);
            }
            curg = g15;
        }
    }
    FLUSH(curg);
#undef FLUSH
}

// ================= head =================
__global__ void head_kernel(
    const float* __restrict__ pooled, const int* __restrict__ batch,
    const float* __restrict__ Wfc, const float* __restrict__ bfc,
    float* __restrict__ out)
{
    int g = threadIdx.x;
    if (g >= NUM_GRAPHS) return;

    int lo = 0, hi = N_NODES;
    while (lo < hi) { int mid = (lo + hi) >> 1; if (batch[mid] < g) lo = mid + 1; else hi = mid; }
    int beg = lo;
    lo = 0; hi = N_NODES;
    while (lo < hi) { int mid = (lo + hi) >> 1; if (batch[mid] < g + 1) lo = mid + 1; else hi = mid; }
    int cnt = lo - beg;
    float inv = 1.0f / fmaxf((float)cnt, 1.0f);

    float logits[10];
    for (int o = 0; o < 10; ++o) {
        float acc = 0.0f;
        for (int k = 0; k < 128; ++k)
            acc = fmaf(pooled[g * 128 + k], Wfc[k * 10 + o], acc);
        logits[o] = acc * inv + bfc[o];
    }
    float m = -INFINITY;
    for (int o = 0; o < 10; ++o) m = fmaxf(m, logits[o]);
    float s = 0.0f;
    for (int o = 0; o < 10; ++o) s += expf(logits[o] - m);
    float ls = logf(s);
    for (int o = 0; o < 10; ++o) out[g * 10 + o] = logits[o] - m - ls;
}

extern "C" void kernel_launch(void* const* d_in, const int* in_sizes, int n_in,
                              void* d_out, int out_size, void* d_ws, size_t ws_size,
                              hipStream_t stream)
{
    const float* x     = (const float*)d_in[0];
    const int*   ei    = (const int*)d_in[1];
    const int*   src   = ei;
    const int*   dst   = ei + N_EDGES;
    const int*   batch = (const int*)d_in[2];
    const float* W1  = (const float*)d_in[3];
    const float* b1  = (const float*)d_in[4];
    const float* W2  = (const float*)d_in[5];
    const float* b2  = (const float*)d_in[6];
    const float* W3  = (const float*)d_in[7];
    const float* b3  = (const float*)d_in[8];
    const float* W4  = (const float*)d_in[9];
    const float* b4  = (const float*)d_in[10];
    const float* Wfc = (const float*)d_in[11];
    const float* bfc = (const float*)d_in[12];
    float* out = (float*)d_out;

    char* ws = (char*)d_ws;
    unsigned char* yfp8 = (unsigned char*)(ws);             // 6.4 MB (fp8 y)
    unsigned char* zfp8 = (unsigned char*)(ws + 6400000);   // 6.4 MB (fp8 z)
    ushort* yagg  = (ushort*)(ws + 12800000);               // 12.8 MB (bf16)
    ushort* zagg  = (ushort*)(ws + 25600000);               // 12.8 MB (bf16)
    int*  esrc    = (int*) (ws + 38400000);                 // 6.4 MB
    uint* epack   = (uint*)(ws + 44800000);                 // 6.4 MB
    int*  rowptr  = (int*) (ws + 51200000);                 // 400,004 B
    int*  bcount  = (int*) (ws + 51600016);                 // 613,088 B
    int*  basetab = (int*) (ws + 52213104);                 // 613,088 B
    int*  btot    = (int*) (ws + 52826192);                 // 784 B
    int*  gbase   = (int*) (ws + 52826976);                 // 788 B
    float* pooled = (float*)(ws + 52827776);                // 32 KB

    // ---- K1: coarse hist + gemm1 (fp8 out) ----
    k1_hist_gemm<<<NB1 + GEMM_GS, 256, 0, stream>>>(dst, bcount, x, W1, yfp8);
    // ---- CSR build ----
    p2a_scan<<<NBUCK, 256, 0, stream>>>(bcount, basetab, btot);
    p2b_scan<<<1, 256, 0, stream>>>(btot, gbase, pooled);
    p3_partition<<<NB1, 256, 0, stream>>>(src, dst, basetab, gbase, epack);
    p4_fine<<<NBUCK, 256, 0, stream>>>(epack, gbase, rowptr, esrc);

    // ---- layer 1 ----
    agg_fp8<<<(N_NODES + AGG_NPB - 1) / AGG_NPB, 256, 0, stream>>>(
        (const uint2*)yfp8, (uint4*)yagg, rowptr, esrc);
    fused_mid<<<GEMM_GS, 256, 0, stream>>>(yagg, b1, W2, b2, W3, zfp8);

    // ---- layer 2 ----
    agg_fp8<<<(N_NODES + AGG_NPB - 1) / AGG_NPB, 256, 0, stream>>>(
        (const uint2*)zfp8, (uint4*)zagg, rowptr, esrc);
    {
        const int NT = N_NODES / 16;   // 6250
        const int TPW = 4;
        int blocks = (NT + 4 * TPW - 1) / (4 * TPW);   // 391
        k4_mfma_pool<<<blocks, 256, 0, stream>>>(zagg, b3, W4, b4, batch, pooled);
    }

    head_kernel<<<1, 64, 0, stream>>>(pooled, batch, Wfc, bfc, out);
}